// Round 3
// baseline (355.524 us; speedup 1.0000x reference)
//
#include <hip/hip_runtime.h>

// Problem: out = u2 + trilinear(u1, grid + u2); B=2, D=H=W=160, C=3, fp32.
constexpr int Bn = 2;
constexpr int Dn = 160;
constexpr int Hn = 160;
constexpr int Wn = 160;
constexpr int NV = Bn * Dn * Hn * Wn;          // 8,192,000 voxels
constexpr int VOL = Dn * Hn * Wn;              // 4,096,000 voxels / batch
constexpr int NBLK = NV / 256;                 // 32000 blocks, exact
constexpr int SLAB = NBLK / 8;                 // 4000 blocks per XCD slab

__global__ __launch_bounds__(256) void compose_transform_kernel(
    const float* __restrict__ warp1,
    const float* __restrict__ warp2,
    float* __restrict__ out) {
    // XCD slab swizzle: blocks go to XCDs round-robin (bid % 8). Remap so
    // each XCD processes a CONTIGUOUS 1/8 of the volume in (d,h,w) order —
    // warp1 gather reuse (h+-1, d+-1 neighbors) then stays inside one XCD's
    // 4 MiB L2 instead of being re-fetched by 3-4 different XCDs.
    int bid  = blockIdx.x;
    int sbid = (bid & 7) * SLAB + (bid >> 3);
    int idx  = sbid * 256 + threadIdx.x;       // voxel id over B*D*H*W

    // decode (b, d, h, w)
    int w  = idx % Wn;
    int t  = idx / Wn;
    int h  = t % Hn;
    t      = t / Hn;
    int d  = t % Dn;
    int b  = t / Dn;

    int base3 = idx * 3;
    // streaming read — nontemporal to keep L2 for the warp1 gathers
    float u2x = __builtin_nontemporal_load(warp2 + base3 + 0);
    float u2y = __builtin_nontemporal_load(warp2 + base3 + 1);
    float u2z = __builtin_nontemporal_load(warp2 + base3 + 2);

    // loc = grid + u2, clipped to [0, size-1]
    float lx = fminf(fmaxf((float)d + u2x, 0.0f), (float)(Dn - 1));
    float ly = fminf(fmaxf((float)h + u2y, 0.0f), (float)(Hn - 1));
    float lz = fminf(fmaxf((float)w + u2z, 0.0f), (float)(Wn - 1));

    // Border-remapped bases: ixb in [0, size-2]; when the reference clamps
    // (lx == size-1) the weight on the extra voxel is exactly 0.
    int ixb = min((int)floorf(lx), Dn - 2);
    int iyb = min((int)floorf(ly), Hn - 2);
    int izb = min((int)floorf(lz), Wn - 2);

    float wx1 = lx - (float)ixb, wx0 = 1.0f - wx1;
    float wy1 = ly - (float)iyb, wy0 = 1.0f - wy1;
    float wz1 = lz - (float)izb, wz0 = 1.0f - wz1;

    const float* __restrict__ u1 = warp1 + b * (VOL * 3);

    // 4 (x,y) rows; each row reads voxels (izb, izb+1) = 6 contiguous floats.
    const float* p00 = u1 + ((ixb       * Hn + iyb    ) * Wn + izb) * 3;
    const float* p01 = u1 + ((ixb       * Hn + iyb + 1) * Wn + izb) * 3;
    const float* p10 = u1 + (((ixb + 1) * Hn + iyb    ) * Wn + izb) * 3;
    const float* p11 = u1 + (((ixb + 1) * Hn + iyb + 1) * Wn + izb) * 3;

    // Issue all gather loads before any use — maximize loads in flight.
    float a00_0 = p00[0], a00_1 = p00[1], a00_2 = p00[2];
    float a00_3 = p00[3], a00_4 = p00[4], a00_5 = p00[5];
    float a01_0 = p01[0], a01_1 = p01[1], a01_2 = p01[2];
    float a01_3 = p01[3], a01_4 = p01[4], a01_5 = p01[5];
    float a10_0 = p10[0], a10_1 = p10[1], a10_2 = p10[2];
    float a10_3 = p10[3], a10_4 = p10[4], a10_5 = p10[5];
    float a11_0 = p11[0], a11_1 = p11[1], a11_2 = p11[2];
    float a11_3 = p11[3], a11_4 = p11[4], a11_5 = p11[5];

    float w00 = wx0 * wy0;
    float w01 = wx0 * wy1;
    float w10 = wx1 * wy0;
    float w11 = wx1 * wy1;

    float rx, ry, rz;
    float accx, accy, accz;

    rx = fmaf(wz1, a00_3, wz0 * a00_0);
    ry = fmaf(wz1, a00_4, wz0 * a00_1);
    rz = fmaf(wz1, a00_5, wz0 * a00_2);
    accx = w00 * rx; accy = w00 * ry; accz = w00 * rz;

    rx = fmaf(wz1, a01_3, wz0 * a01_0);
    ry = fmaf(wz1, a01_4, wz0 * a01_1);
    rz = fmaf(wz1, a01_5, wz0 * a01_2);
    accx = fmaf(w01, rx, accx); accy = fmaf(w01, ry, accy); accz = fmaf(w01, rz, accz);

    rx = fmaf(wz1, a10_3, wz0 * a10_0);
    ry = fmaf(wz1, a10_4, wz0 * a10_1);
    rz = fmaf(wz1, a10_5, wz0 * a10_2);
    accx = fmaf(w10, rx, accx); accy = fmaf(w10, ry, accy); accz = fmaf(w10, rz, accz);

    rx = fmaf(wz1, a11_3, wz0 * a11_0);
    ry = fmaf(wz1, a11_4, wz0 * a11_1);
    rz = fmaf(wz1, a11_5, wz0 * a11_2);
    accx = fmaf(w11, rx, accx); accy = fmaf(w11, ry, accy); accz = fmaf(w11, rz, accz);

    // streaming write — nontemporal
    __builtin_nontemporal_store(u2x + accx, out + base3 + 0);
    __builtin_nontemporal_store(u2y + accy, out + base3 + 1);
    __builtin_nontemporal_store(u2z + accz, out + base3 + 2);
}

extern "C" void kernel_launch(void* const* d_in, const int* in_sizes, int n_in,
                              void* d_out, int out_size, void* d_ws, size_t ws_size,
                              hipStream_t stream) {
    const float* warp1 = (const float*)d_in[0];
    const float* warp2 = (const float*)d_in[1];
    float* out = (float*)d_out;

    compose_transform_kernel<<<NBLK, 256, 0, stream>>>(warp1, warp2, out);
}